// Round 9
// baseline (2614.428 us; speedup 1.0000x reference)
//
#include <hip/hip_runtime.h>
#include <cstdint>
#include <cstddef>

typedef float    float4v __attribute__((ext_vector_type(4)));
typedef _Float16 f16x4   __attribute__((ext_vector_type(4)));
typedef _Float16 f16x8   __attribute__((ext_vector_type(8)));
typedef unsigned long long u64;
struct u64p { u64 a, b; };

#define DI __device__ __forceinline__

static const int Bsz = 64, Tlen = 2048, Hd = 128;
static const int HSTR = 144;   // H row stride (f16): 0 bank conflicts (R7)
static const int RING = 256;   // ring length (steps)
static const int YSTR = 136;   // helper LDS row stride (f16)

DI float sigf_fast(float x) {
    float e = __builtin_amdgcn_exp2f(-1.442695041f * x);
    return __builtin_amdgcn_rcpf(1.f + e);
}
DI float tanhf_fast(float x) {
    float e = __builtin_amdgcn_exp2f(-2.885390082f * x);
    return 2.f * __builtin_amdgcn_rcpf(1.f + e) - 1.f;
}

DI void lds_barrier() {
    asm volatile("s_waitcnt lgkmcnt(0)\n\ts_barrier" ::: "memory");
}

DI void pin(f16x8& v) {
    float4v t = __builtin_bit_cast(float4v, v);
    asm volatile("" : "+v"(t));
    v = __builtin_bit_cast(f16x8, t);
}

DI f16x8 cvt8(const float* p) {
    float4v u = *(const float4v*)p;
    float4v w = *(const float4v*)(p + 4);
    f16x8 o;
    o[0] = (_Float16)u[0]; o[1] = (_Float16)u[1]; o[2] = (_Float16)u[2]; o[3] = (_Float16)u[3];
    o[4] = (_Float16)w[0]; o[5] = (_Float16)w[1]; o[6] = (_Float16)w[2]; o[7] = (_Float16)w[3];
    return o;
}

DI u64 pack4(float4v a) {
    f16x4 h;
    h[0] = (_Float16)a[0]; h[1] = (_Float16)a[1];
    h[2] = (_Float16)a[2]; h[3] = (_Float16)a[3];
    return __builtin_bit_cast(u64, h);
}

DI u64 ald64(const void* pp) {
    return __hip_atomic_load((const u64*)pp, __ATOMIC_RELAXED, __HIP_MEMORY_SCOPE_AGENT);
}
DI void ast64(void* pp, u64 v) {
    __hip_atomic_store((u64*)pp, v, __ATOMIC_RELAXED, __HIP_MEMORY_SCOPE_AGENT);
}
DI void ast16(void* pp, unsigned short v) {
    __hip_atomic_store((unsigned short*)pp, v, __ATOMIC_RELAXED, __HIP_MEMORY_SCOPE_AGENT);
}
DI unsigned int aldu32(const unsigned int* pp) {
    return __hip_atomic_load(pp, __ATOMIC_RELAXED, __HIP_MEMORY_SCOPE_AGENT);
}
DI void astu32(unsigned int* pp, unsigned int v) {
    __hip_atomic_store(pp, v, __ATOMIC_RELAXED, __HIP_MEMORY_SCOPE_AGENT);
}

// ---------------------------------------------------------------------------
// R17: mega-kernel with 4-WAVE (256-thread) WGs.
// R16 post-mortem: active-CU VALU/MFMA util ~19/18% -> step latency-bound on
// the 8-wave structure (2 barrier-locked waves per SIMD serialize issue and
// double barrier skew). Fix: each recurrence wave carries 8 m-tiles
// (af[8][4] = 128 VGPR) -> 4 waves cover all 512 gate rows; 1 wave/SIMD.
// Each thread owns TWO gate-sets: mt=s (j = w*32+s*4+quad) and mt=s+4 (j+16).
// Per-step publishes/loads double (2 each); vmcnt release counts: enc 4, dec
// stores-only 2, consumer-dec 4. Helper/xph/out re-tiled for 256 thr
// (nt 0..7 / 2-row staging / 2x stores) -- off critical path. prog
// numerology identical to R16.
// ---------------------------------------------------------------------------
__global__ __launch_bounds__(256, 1) void lstm_mega(
    const float* __restrict__ eU0, const float* __restrict__ eb0i, const float* __restrict__ eb0h,
    const float* __restrict__ dU0, const float* __restrict__ db0i, const float* __restrict__ db0h,
    const float* __restrict__ eU1, const float* __restrict__ eb1i, const float* __restrict__ eb1h,
    const float* __restrict__ dU1, const float* __restrict__ db1i, const float* __restrict__ db1h,
    const float* __restrict__ eW1, const float* __restrict__ dW1,
    const float* __restrict__ eW0, const float* __restrict__ xin,
    const float* __restrict__ oW,  const float* __restrict__ ob,
    float* __restrict__ outp,
    _Float16* __restrict__ PB,          // y0 ring  [64][RING][128] f16
    _Float16* __restrict__ X2,          // xp2 ring [64][RING][512] f16 (PERM)
    _Float16* __restrict__ X1,          // xp  ring [64][RING][512] f16 (PERM)
    _Float16* __restrict__ Y1,          // y1  ring [64][RING][128] f16
    unsigned int* __restrict__ prog,  unsigned int* __restrict__ prog2,
    unsigned int* __restrict__ prog3, unsigned int* __restrict__ prog4,
    unsigned int* __restrict__ prog5, int T)
{
    const int tid  = threadIdx.x;
    const int lane = tid & 63, w = tid >> 6;     // 4 waves
    const int col  = lane & 15, quad = lane >> 4;
    const int b    = col & 3, s = col >> 2;
    const int role = blockIdx.x >> 4;            // 0 prod, 1 cons, 2 Wih, 3 xph, 4 out
    const int p    = blockIdx.x & 15;
    const int bglob = p * 4 + b;
    const int jA   = w * 32 + s * 4 + quad;      // owned gate-set A (mt=s)
    const int jB   = jA + 16;                    // owned gate-set B (mt=s+4)
    const int NG   = T >> 3;
    const int NG2  = NG * 2;
    const unsigned int T2 = (unsigned int)(2 * T);

    __shared__ alignas(16) _Float16 Hl[2 * 4 * HSTR];
    __shared__ alignas(16) _Float16 Ylh[32 * YSTR];

    unsigned int* pr  = prog  + p * 16;
    unsigned int* pr2 = prog2 + p * 16;
    unsigned int* pr3 = prog3 + p * 16;
    unsigned int* pr4 = prog4 + p * 16;
    unsigned int* pr5 = prog5 + p * 16;

    if (role == 0) {
        // ================= producer: encL0 then decL0 (4 waves) ===========
        f16x8 af[8][4];
        float bqA[4], bqB[4];
#pragma unroll
        for (int mt = 0; mt < 8; mt++) {
            int urow = (col & 3) * 128 + (w * 32 + mt * 4 + (col >> 2));
            const float* ur = eU0 + (size_t)urow * 128;
#pragma unroll
            for (int kc = 0; kc < 4; kc++) { af[mt][kc] = cvt8(ur + kc * 32 + quad * 8); pin(af[mt][kc]); }
        }
#pragma unroll
        for (int q = 0; q < 4; q++) {
            bqA[q] = eb0i[q * 128 + jA] + eb0h[q * 128 + jA];
            bqB[q] = eb0i[q * 128 + jB] + eb0h[q * 128 + jB];
        }

        float cA = 0.f, hA = 0.f, cB = 0.f, hB = 0.f;
        Hl[b * HSTR + jA] = (_Float16)0.f;
        Hl[b * HSTR + jB] = (_Float16)0.f;
        __syncthreads();

        const _Float16* x1bA = X1 + (size_t)bglob * RING * 512 + 4 * jA;
        const _Float16* x1bB = x1bA + 64;
        unsigned short* pbpA = (unsigned short*)PB + (size_t)bglob * RING * 128 + jA;
        unsigned short* pbpB = pbpA + 16;

        if (tid == 255) {
            unsigned int need = 16u; if (need > (unsigned int)T) need = (unsigned int)T;
            unsigned int psn = aldu32(pr3);
            while (psn < need) { __builtin_amdgcn_s_sleep(8); psn = aldu32(pr3); }
        }
        __syncthreads();
        f16x4 xpA = __builtin_bit_cast(f16x4, ald64(x1bA));
        f16x4 xpB = __builtin_bit_cast(f16x4, ald64(x1bB));

        int cur = 0;
        unsigned int pf3 = 0, ps3 = 0;
        for (int g = 0; g < NG2; g++) {
            if (g == NG) {
#pragma unroll
                for (int mt = 0; mt < 8; mt++) {
                    int urow = (col & 3) * 128 + (w * 32 + mt * 4 + (col >> 2));
                    const float* ur = dU0 + (size_t)urow * 128;
#pragma unroll
                    for (int kc = 0; kc < 4; kc++) { af[mt][kc] = cvt8(ur + kc * 32 + quad * 8); pin(af[mt][kc]); }
                }
#pragma unroll
                for (int q = 0; q < 4; q++) {
                    bqA[q] = db0i[q * 128 + jA] + db0h[q * 128 + jA];
                    bqB[q] = db0i[q * 128 + jB] + db0h[q * 128 + jB];
                }
            }
            if (g < NG) {
                if (tid == 255 && g + 1 < NG) pf3 = aldu32(pr3);
#pragma unroll
                for (int k = 0; k < 8; k++) {
                    const int t = g * 8 + k;
                    const size_t nsl = (size_t)((t + 1) & (RING - 1)) * 512;
                    f16x4 xpnA = __builtin_bit_cast(f16x4, ald64(x1bA + nsl));
                    f16x4 xpnB = __builtin_bit_cast(f16x4, ald64(x1bB + nsl));

                    const _Float16* Hc = Hl + cur * (4 * HSTR);
                    f16x8 bf[4];
#pragma unroll
                    for (int kc = 0; kc < 4; kc++)
                        bf[kc] = *(const f16x8*)(Hc + b * HSTR + kc * 32 + quad * 8);

                    float4v acc[8] = {};
#pragma unroll
                    for (int kc = 0; kc < 4; kc++)
#pragma unroll
                        for (int mt = 0; mt < 8; mt++)
                            acc[mt] = __builtin_amdgcn_mfma_f32_16x16x32_f16(af[mt][kc], bf[kc], acc[mt], 0, 0, 0);

                    float4v u0 = (s & 1) ? acc[1] : acc[0];
                    float4v u1 = (s & 1) ? acc[3] : acc[2];
                    float4v gA = (s & 2) ? u1 : u0;
                    float4v u2 = (s & 1) ? acc[5] : acc[4];
                    float4v u3 = (s & 1) ? acc[7] : acc[6];
                    float4v gB = (s & 2) ? u3 : u2;

                    float a0 = gA[0] + bqA[0] + (float)xpA[0], a1 = gA[1] + bqA[1] + (float)xpA[1];
                    float a2 = gA[2] + bqA[2] + (float)xpA[2], a3 = gA[3] + bqA[3] + (float)xpA[3];
                    float iA = sigf_fast(a0), fA = sigf_fast(a1);
                    float gvA = tanhf_fast(a2), oA = sigf_fast(a3);
                    cA = fA * cA + iA * gvA;
                    hA = oA * tanhf_fast(cA);

                    float b0 = gB[0] + bqB[0] + (float)xpB[0], b1 = gB[1] + bqB[1] + (float)xpB[1];
                    float b2 = gB[2] + bqB[2] + (float)xpB[2], b3 = gB[3] + bqB[3] + (float)xpB[3];
                    float iB = sigf_fast(b0), fB = sigf_fast(b1);
                    float gvB = tanhf_fast(b2), oB = sigf_fast(b3);
                    cB = fB * cB + iB * gvB;
                    hB = oB * tanhf_fast(cB);

                    _Float16 hfA = (_Float16)hA, hfB = (_Float16)hB;
                    _Float16* Hn = Hl + (cur ^ 1) * (4 * HSTR) + b * HSTR;
                    Hn[jA] = hfA;
                    Hn[jB] = hfB;
                    const size_t sl = (size_t)(t & (RING - 1)) * 128;
                    ast16(pbpA + sl, __builtin_bit_cast(unsigned short, hfA));
                    ast16(pbpB + sl, __builtin_bit_cast(unsigned short, hfB));

                    if (k == 7) {
                        // newest {2 xploads, 2 PBstores} may remain -> y(<=8g+6) ACKed
                        asm volatile("s_waitcnt vmcnt(4)" ::: "memory");
                        if (tid == 0) astu32(pr, (unsigned int)(g * 8 + 7));
                        if (tid == 255 && g + 1 < NG) {
                            unsigned int need = (unsigned int)(8 * (g + 1) + 16);
                            if (need > (unsigned int)T) need = (unsigned int)T;
                            if (ps3 < pf3) ps3 = pf3;
                            while (ps3 < need) { __builtin_amdgcn_s_sleep(2); ps3 = aldu32(pr3); }
                        }
                    }
                    lds_barrier();
                    xpA = xpnA; xpB = xpnB;
                    cur ^= 1;
                }
            } else {
#pragma unroll
                for (int k = 0; k < 8; k++) {
                    const int t = g * 8 + k;

                    const _Float16* Hc = Hl + cur * (4 * HSTR);
                    f16x8 bf[4];
#pragma unroll
                    for (int kc = 0; kc < 4; kc++)
                        bf[kc] = *(const f16x8*)(Hc + b * HSTR + kc * 32 + quad * 8);

                    float4v acc[8] = {};
#pragma unroll
                    for (int kc = 0; kc < 4; kc++)
#pragma unroll
                        for (int mt = 0; mt < 8; mt++)
                            acc[mt] = __builtin_amdgcn_mfma_f32_16x16x32_f16(af[mt][kc], bf[kc], acc[mt], 0, 0, 0);

                    float4v u0 = (s & 1) ? acc[1] : acc[0];
                    float4v u1 = (s & 1) ? acc[3] : acc[2];
                    float4v gA = (s & 2) ? u1 : u0;
                    float4v u2 = (s & 1) ? acc[5] : acc[4];
                    float4v u3 = (s & 1) ? acc[7] : acc[6];
                    float4v gB = (s & 2) ? u3 : u2;

                    float a0 = gA[0] + bqA[0], a1 = gA[1] + bqA[1];
                    float a2 = gA[2] + bqA[2], a3 = gA[3] + bqA[3];
                    float iA = sigf_fast(a0), fA = sigf_fast(a1);
                    float gvA = tanhf_fast(a2), oA = sigf_fast(a3);
                    cA = fA * cA + iA * gvA;
                    hA = oA * tanhf_fast(cA);

                    float b0 = gB[0] + bqB[0], b1 = gB[1] + bqB[1];
                    float b2 = gB[2] + bqB[2], b3 = gB[3] + bqB[3];
                    float iB = sigf_fast(b0), fB = sigf_fast(b1);
                    float gvB = tanhf_fast(b2), oB = sigf_fast(b3);
                    cB = fB * cB + iB * gvB;
                    hB = oB * tanhf_fast(cB);

                    _Float16 hfA = (_Float16)hA, hfB = (_Float16)hB;
                    _Float16* Hn = Hl + (cur ^ 1) * (4 * HSTR) + b * HSTR;
                    Hn[jA] = hfA;
                    Hn[jB] = hfB;
                    const size_t sl = (size_t)(t & (RING - 1)) * 128;
                    ast16(pbpA + sl, __builtin_bit_cast(unsigned short, hfA));
                    ast16(pbpB + sl, __builtin_bit_cast(unsigned short, hfB));

                    if (k == 7) {
                        asm volatile("s_waitcnt vmcnt(2)" ::: "memory");
                        if (tid == 0) astu32(pr, (unsigned int)(g * 8 + 7));
                    }
                    lds_barrier();
                    cur ^= 1;
                }
            }
        }
        asm volatile("s_waitcnt vmcnt(0)" ::: "memory");
        __syncthreads();
        if (tid == 0) astu32(pr, T2);
    } else if (role == 1) {
        // ================= consumer: encL1 then decL1 (4 waves) ===========
        f16x8 afH[8][4];
        float bqA[4], bqB[4];
#pragma unroll
        for (int mt = 0; mt < 8; mt++) {
            int urow = (col & 3) * 128 + (w * 32 + mt * 4 + (col >> 2));
            const float* ur = eU1 + (size_t)urow * 128;
#pragma unroll
            for (int kc = 0; kc < 4; kc++) { afH[mt][kc] = cvt8(ur + kc * 32 + quad * 8); pin(afH[mt][kc]); }
        }
#pragma unroll
        for (int q = 0; q < 4; q++) {
            bqA[q] = eb1i[q * 128 + jA] + eb1h[q * 128 + jA];
            bqB[q] = eb1i[q * 128 + jB] + eb1h[q * 128 + jB];
        }

        float cA = 0.f, hA = 0.f, cB = 0.f, hB = 0.f;
        Hl[b * HSTR + jA] = (_Float16)0.f;
        Hl[b * HSTR + jB] = (_Float16)0.f;

        if (tid == 255) {
            unsigned int need = 9u; if (need > T2) need = T2;
            unsigned int psn = aldu32(pr2);
            while (psn < need) { __builtin_amdgcn_s_sleep(8); psn = aldu32(pr2); }
        }
        __syncthreads();

        const _Float16* x2bA = X2 + (size_t)bglob * RING * 512 + 4 * jA;
        const _Float16* x2bB = x2bA + 64;
        unsigned short* y1pA = (unsigned short*)Y1 + (size_t)bglob * RING * 128 + jA;
        unsigned short* y1pB = y1pA + 16;
        f16x4 xpA = __builtin_bit_cast(f16x4, ald64(x2bA));
        f16x4 xpB = __builtin_bit_cast(f16x4, ald64(x2bB));

        int cur = 0;
        unsigned int pf2 = 0, ps2 = 0, pf5 = 0, ps5 = 0;
        for (int g = 0; g < NG2; g++) {
            if (g == NG) {
#pragma unroll
                for (int mt = 0; mt < 8; mt++) {
                    int urow = (col & 3) * 128 + (w * 32 + mt * 4 + (col >> 2));
                    const float* ur = dU1 + (size_t)urow * 128;
#pragma unroll
                    for (int kc = 0; kc < 4; kc++) { afH[mt][kc] = cvt8(ur + kc * 32 + quad * 8); pin(afH[mt][kc]); }
                }
#pragma unroll
                for (int q = 0; q < 4; q++) {
                    bqA[q] = db1i[q * 128 + jA] + db1h[q * 128 + jA];
                    bqB[q] = db1i[q * 128 + jB] + db1h[q * 128 + jB];
                }
            }
            if (tid == 255) {
                if (g + 1 < NG2) pf2 = aldu32(pr2);
                if (g + 1 >= NG + 32 && g + 1 < NG2) pf5 = aldu32(pr5);
            }
            const bool isDec = (g >= NG);
#pragma unroll
            for (int k = 0; k < 8; k++) {
                const int t = g * 8 + k;
                const size_t nsl = (size_t)((t + 1) & (RING - 1)) * 512;
                f16x4 xpnA = __builtin_bit_cast(f16x4, ald64(x2bA + nsl));
                f16x4 xpnB = __builtin_bit_cast(f16x4, ald64(x2bB + nsl));

                const _Float16* Hc = Hl + cur * (4 * HSTR);
                f16x8 bf[4];
#pragma unroll
                for (int kc = 0; kc < 4; kc++)
                    bf[kc] = *(const f16x8*)(Hc + b * HSTR + kc * 32 + quad * 8);

                float4v acc[8] = {};
#pragma unroll
                for (int kc = 0; kc < 4; kc++)
#pragma unroll
                    for (int mt = 0; mt < 8; mt++)
                        acc[mt] = __builtin_amdgcn_mfma_f32_16x16x32_f16(afH[mt][kc], bf[kc], acc[mt], 0, 0, 0);

                float4v u0 = (s & 1) ? acc[1] : acc[0];
                float4v u1 = (s & 1) ? acc[3] : acc[2];
                float4v gA = (s & 2) ? u1 : u0;
                float4v u2 = (s & 1) ? acc[5] : acc[4];
                float4v u3 = (s & 1) ? acc[7] : acc[6];
                float4v gB = (s & 2) ? u3 : u2;

                float a0 = gA[0] + bqA[0] + (float)xpA[0], a1 = gA[1] + bqA[1] + (float)xpA[1];
                float a2 = gA[2] + bqA[2] + (float)xpA[2], a3 = gA[3] + bqA[3] + (float)xpA[3];
                float iA = sigf_fast(a0), fA = sigf_fast(a1);
                float gvA = tanhf_fast(a2), oA = sigf_fast(a3);
                cA = fA * cA + iA * gvA;
                hA = oA * tanhf_fast(cA);

                float b0 = gB[0] + bqB[0] + (float)xpB[0], b1 = gB[1] + bqB[1] + (float)xpB[1];
                float b2 = gB[2] + bqB[2] + (float)xpB[2], b3 = gB[3] + bqB[3] + (float)xpB[3];
                float iB = sigf_fast(b0), fB = sigf_fast(b1);
                float gvB = tanhf_fast(b2), oB = sigf_fast(b3);
                cB = fB * cB + iB * gvB;
                hB = oB * tanhf_fast(cB);

                _Float16 hfA = (_Float16)hA, hfB = (_Float16)hB;
                _Float16* Hn = Hl + (cur ^ 1) * (4 * HSTR) + b * HSTR;
                Hn[jA] = hfA;
                Hn[jB] = hfB;
                if (isDec) {
                    const size_t sl = (size_t)(t & (RING - 1)) * 128;
                    ast16(y1pA + sl, __builtin_bit_cast(unsigned short, hfA));
                    ast16(y1pB + sl, __builtin_bit_cast(unsigned short, hfB));
                }

                if (k == 7) {
                    if (isDec) {
                        // newest {2 xp2loads, 2 y1stores} remain
                        asm volatile("s_waitcnt vmcnt(4)" ::: "memory");
                        if (tid == 0) astu32(pr4, (unsigned int)(g * 8 + 7));
                    }
                    if (tid == 255 && g + 1 < NG2) {
                        unsigned int need = (unsigned int)(8 * (g + 1) + 9);
                        if (need > T2) need = T2;
                        if (ps2 < pf2) ps2 = pf2;
                        while (ps2 < need) { __builtin_amdgcn_s_sleep(2); ps2 = aldu32(pr2); }
                        if (isDec && g + 1 >= NG + 32) {
                            unsigned int need5 = (unsigned int)(8 * (g + 1 - 32) + 8);
                            if (ps5 < pf5) ps5 = pf5;
                            while (ps5 < need5) { __builtin_amdgcn_s_sleep(2); ps5 = aldu32(pr5); }
                        }
                    }
                }
                lds_barrier();
                xpA = xpnA; xpB = xpnB;
                cur ^= 1;
            }
        }
        asm volatile("s_waitcnt vmcnt(0)" ::: "memory");
        __syncthreads();
        if (tid == 0) astu32(pr4, T2);
    } else if (role == 2) {
        // ========== Wih-helper (4 waves, nt 0..7), 2T granules ============
        f16x8 bw[8][4];
#pragma unroll
        for (int nt = 0; nt < 8; nt++) {
            int n = (w * 8 + nt) * 16 + col;
            int wrow = (n & 3) * 128 + (n >> 2);
            const float* Wr = eW1 + (size_t)wrow * 128;
#pragma unroll
            for (int kc = 0; kc < 4; kc++) { bw[nt][kc] = cvt8(Wr + kc * 32 + quad * 8); pin(bw[nt][kc]); }
        }

        const int lrow0 = tid >> 4, lchunk = tid & 15;

        for (int g = 0; g < NG2; g++) {
            if (g == NG) {
#pragma unroll
                for (int nt = 0; nt < 8; nt++) {
                    int n = (w * 8 + nt) * 16 + col;
                    int wrow = (n & 3) * 128 + (n >> 2);
                    const float* Wr = dW1 + (size_t)wrow * 128;
#pragma unroll
                    for (int kc = 0; kc < 4; kc++) { bw[nt][kc] = cvt8(Wr + kc * 32 + quad * 8); pin(bw[nt][kc]); }
                }
            }
            if (tid == 0) {
                unsigned int need = (unsigned int)(g * 8 + 8);
                unsigned int psn = aldu32(pr);
                while (psn < need) { __builtin_amdgcn_s_sleep(4); psn = aldu32(pr); }
            }
            __syncthreads();
#pragma unroll
            for (int rr = 0; rr < 2; rr++) {
                int row = lrow0 + rr * 16;
                int lb = row & 3, ltr = row >> 2;
                int slot = (g * 8 + ltr) & (RING - 1);
                const char* srcp = (const char*)(PB + ((size_t)(p * 4 + lb) * RING + slot) * 128 + lchunk * 8);
                u64 a0 = ald64(srcp);
                u64 a1 = ald64(srcp + 8);
                char* dst = (char*)&Ylh[row * YSTR + lchunk * 8];
                *(u64*)dst = a0;
                *(u64*)(dst + 8) = a1;
            }
            lds_barrier();

            float4v acc[2][8] = {};
#pragma unroll
            for (int kc = 0; kc < 4; kc++) {
                f16x8 y0  = *(const f16x8*)&Ylh[col * YSTR + kc * 32 + quad * 8];
                f16x8 y1t = *(const f16x8*)&Ylh[(16 + col) * YSTR + kc * 32 + quad * 8];
#pragma unroll
                for (int nt = 0; nt < 8; nt++) {
                    acc[0][nt] = __builtin_amdgcn_mfma_f32_16x16x32_f16(bw[nt][kc], y0,  acc[0][nt], 0, 0, 0);
                    acc[1][nt] = __builtin_amdgcn_mfma_f32_16x16x32_f16(bw[nt][kc], y1t, acc[1][nt], 0, 0, 0);
                }
            }
            {
                const int bb = col & 3;
#pragma unroll
                for (int mt = 0; mt < 2; mt++) {
                    int trow = mt * 4 + (col >> 2);
                    int slot = (g * 8 + trow) & (RING - 1);
                    _Float16* dst = X2 + ((size_t)(p * 4 + bb) * RING + slot) * 512 + (w * 8) * 16 + quad * 4;
#pragma unroll
                    for (int nt = 0; nt < 8; nt++)
                        ast64(dst + nt * 16, pack4(acc[mt][nt]));
                }
            }
            asm volatile("s_waitcnt vmcnt(0)" ::: "memory");
            __syncthreads();
            if (tid == 0) astu32(pr2, (unsigned int)(g * 8 + 8));
        }
    } else if (role == 3) {
        // ========== xph (4 waves, nt 0..7): x @ eW0^T -> X1, exits at NG ==
        f16x8 bw[8][4];
#pragma unroll
        for (int nt = 0; nt < 8; nt++) {
            int n = (w * 8 + nt) * 16 + col;
            int wrow = (n & 3) * 128 + (n >> 2);
            const float* Wr = eW0 + (size_t)wrow * 128;
#pragma unroll
            for (int kc = 0; kc < 4; kc++) { bw[nt][kc] = cvt8(Wr + kc * 32 + quad * 8); pin(bw[nt][kc]); }
        }

        const int lrow0 = tid >> 4, lchunk = tid & 15;

        for (int g = 0; g < NG; g++) {
            if (g >= 32 && tid == 0) {
                unsigned int need = (unsigned int)(8 * (g - 32));
                unsigned int psn = aldu32(pr);
                while (psn < need) { __builtin_amdgcn_s_sleep(4); psn = aldu32(pr); }
            }
            __syncthreads();
#pragma unroll
            for (int rr = 0; rr < 2; rr++) {
                int row = lrow0 + rr * 16;
                int lb = row & 3, ltr = row >> 2;
                f16x8 xv = cvt8(xin + ((size_t)(p * 4 + lb) * T + g * 8 + ltr) * 128 + lchunk * 8);
                u64p w2 = __builtin_bit_cast(u64p, xv);
                char* dst = (char*)&Ylh[row * YSTR + lchunk * 8];
                *(u64*)dst = w2.a;
                *(u64*)(dst + 8) = w2.b;
            }
            lds_barrier();

            float4v acc[2][8] = {};
#pragma unroll
            for (int kc = 0; kc < 4; kc++) {
                f16x8 y0  = *(const f16x8*)&Ylh[col * YSTR + kc * 32 + quad * 8];
                f16x8 y1t = *(const f16x8*)&Ylh[(16 + col) * YSTR + kc * 32 + quad * 8];
#pragma unroll
                for (int nt = 0; nt < 8; nt++) {
                    acc[0][nt] = __builtin_amdgcn_mfma_f32_16x16x32_f16(bw[nt][kc], y0,  acc[0][nt], 0, 0, 0);
                    acc[1][nt] = __builtin_amdgcn_mfma_f32_16x16x32_f16(bw[nt][kc], y1t, acc[1][nt], 0, 0, 0);
                }
            }
            {
                const int bb = col & 3;
#pragma unroll
                for (int mt = 0; mt < 2; mt++) {
                    int trow = mt * 4 + (col >> 2);
                    int slot = (g * 8 + trow) & (RING - 1);
                    _Float16* dst = X1 + ((size_t)(p * 4 + bb) * RING + slot) * 512 + (w * 8) * 16 + quad * 4;
#pragma unroll
                    for (int nt = 0; nt < 8; nt++)
                        ast64(dst + nt * 16, pack4(acc[mt][nt]));
                }
            }
            asm volatile("s_waitcnt vmcnt(0)" ::: "memory");
            __syncthreads();
            if (tid == 0) astu32(pr3, (unsigned int)(g * 8 + 8));
        }
    } else {
        // ========== out (4 waves, nt 0..1): y1 @ oW^T + ob -> d_out =======
        f16x8 bo[2][4];
        float4v bv4[2];
#pragma unroll
        for (int nt = 0; nt < 2; nt++) {
            const float* Wr = oW + (size_t)(w * 32 + nt * 16 + col) * 128;
#pragma unroll
            for (int kc = 0; kc < 4; kc++) { bo[nt][kc] = cvt8(Wr + kc * 32 + quad * 8); pin(bo[nt][kc]); }
            bv4[nt] = *(const float4v*)(ob + w * 32 + nt * 16 + quad * 4);
        }

        const int lrow0 = tid >> 4, lchunk = tid & 15;

        for (int gg = 0; gg < NG; gg++) {
            const int g = NG + gg;
            if (tid == 0) {
                unsigned int need = (unsigned int)(g * 8 + 8);
                unsigned int psn = aldu32(pr4);
                while (psn < need) { __builtin_amdgcn_s_sleep(4); psn = aldu32(pr4); }
            }
            __syncthreads();
#pragma unroll
            for (int rr = 0; rr < 2; rr++) {
                int row = lrow0 + rr * 16;
                int lb = row & 3, ltr = row >> 2;
                int slot = (g * 8 + ltr) & (RING - 1);
                const char* srcp = (const char*)(Y1 + ((size_t)(p * 4 + lb) * RING + slot) * 128 + lchunk * 8);
                u64 a0 = ald64(srcp);
                u64 a1 = ald64(srcp + 8);
                char* dst = (char*)&Ylh[row * YSTR + lchunk * 8];
                *(u64*)dst = a0;
                *(u64*)(dst + 8) = a1;
            }
            lds_barrier();
            if (tid == 0) astu32(pr5, (unsigned int)(g * 8 + 8));

            float4v acc[2][2] = {};
#pragma unroll
            for (int kc = 0; kc < 4; kc++) {
                f16x8 y0  = *(const f16x8*)&Ylh[col * YSTR + kc * 32 + quad * 8];
                f16x8 y1t = *(const f16x8*)&Ylh[(16 + col) * YSTR + kc * 32 + quad * 8];
#pragma unroll
                for (int nt = 0; nt < 2; nt++) {
                    acc[0][nt] = __builtin_amdgcn_mfma_f32_16x16x32_f16(bo[nt][kc], y0,  acc[0][nt], 0, 0, 0);
                    acc[1][nt] = __builtin_amdgcn_mfma_f32_16x16x32_f16(bo[nt][kc], y1t, acc[1][nt], 0, 0, 0);
                }
            }
            {
                const int bb = col & 3;
#pragma unroll
                for (int mt = 0; mt < 2; mt++) {
                    int trow = mt * 4 + (col >> 2);
#pragma unroll
                    for (int nt = 0; nt < 2; nt++) {
                        float4v v = acc[mt][nt];
                        v[0] += bv4[nt][0]; v[1] += bv4[nt][1];
                        v[2] += bv4[nt][2]; v[3] += bv4[nt][3];
                        *(float4v*)(outp + ((size_t)(p * 4 + bb) * T + gg * 8 + trow) * 128
                                    + w * 32 + nt * 16 + quad * 4) = v;
                    }
                }
            }
        }
    }
}

// ---------------------------------------------------------------------------
// Host: memset + ONE launch (80 WGs x 256 threads).
//   ws map: X1 [0,16M) | X2 [16,32M) | PB [32,36M) | Y1 [36,40M) | prog @40M
// ---------------------------------------------------------------------------
extern "C" void kernel_launch(void* const* d_in, const int* in_sizes, int n_in,
                              void* d_out, int out_size, void* d_ws, size_t ws_size,
                              hipStream_t stream)
{
    const float* x    = (const float*)d_in[0];
    const float* eW0  = (const float*)d_in[1];
    const float* eU0  = (const float*)d_in[2];
    const float* eb0i = (const float*)d_in[3];
    const float* eb0h = (const float*)d_in[4];
    const float* eW1  = (const float*)d_in[5];
    const float* eU1  = (const float*)d_in[6];
    const float* eb1i = (const float*)d_in[7];
    const float* eb1h = (const float*)d_in[8];
    const float* dU0  = (const float*)d_in[10];
    const float* db0i = (const float*)d_in[11];
    const float* db0h = (const float*)d_in[12];
    const float* dW1  = (const float*)d_in[13];
    const float* dU1  = (const float*)d_in[14];
    const float* db1i = (const float*)d_in[15];
    const float* db1h = (const float*)d_in[16];
    const float* oW   = (const float*)d_in[17];
    const float* ob   = (const float*)d_in[18];

    char* ws = (char*)d_ws;
    _Float16* X1 = (_Float16*)(ws);                  // 16MB
    _Float16* X2 = (_Float16*)(ws + (16u << 20));    // 16MB
    _Float16* PB = (_Float16*)(ws + (32u << 20));    //  4MB
    _Float16* Y1 = (_Float16*)(ws + (36u << 20));    //  4MB
    unsigned int* pg = (unsigned int*)(ws + (40u << 20));

    hipMemsetAsync((void*)pg, 0, 8192, stream);

    lstm_mega<<<dim3(80), dim3(256), 0, stream>>>(
        eU0, eb0i, eb0h, dU0, db0i, db0h,
        eU1, eb1i, eb1h, dU1, db1i, db1h,
        eW1, dW1, eW0, x, oW, ob, (float*)d_out,
        PB, X2, X1, Y1,
        pg, pg + 256, pg + 512, pg + 768, pg + 1024, Tlen);
}

// Round 10
// 2472.013 us; speedup vs baseline: 1.0576x; 1.0576x over previous
//
#include <hip/hip_runtime.h>
#include <cstdint>
#include <cstddef>

typedef float    float4v __attribute__((ext_vector_type(4)));
typedef _Float16 f16x4   __attribute__((ext_vector_type(4)));
typedef _Float16 f16x8   __attribute__((ext_vector_type(8)));
typedef unsigned long long u64;
struct u64p { u64 a, b; };

#define DI __device__ __forceinline__

static const int Bsz = 64, Tlen = 2048, Hd = 128;
static const int HSTR = 144;   // H row stride (f16): 0 bank conflicts (R7)
static const int RING = 256;   // ring length (steps)
static const int YSTR = 136;   // helper LDS row stride (f16)

DI float sigf_fast(float x) {
    float e = __builtin_amdgcn_exp2f(-1.442695041f * x);
    return __builtin_amdgcn_rcpf(1.f + e);
}
DI float tanhf_fast(float x) {
    float e = __builtin_amdgcn_exp2f(-2.885390082f * x);
    return 2.f * __builtin_amdgcn_rcpf(1.f + e) - 1.f;
}

DI void lds_barrier() {
    asm volatile("s_waitcnt lgkmcnt(0)\n\ts_barrier" ::: "memory");
}

DI void pin(f16x8& v) {
    float4v t = __builtin_bit_cast(float4v, v);
    asm volatile("" : "+v"(t));
    v = __builtin_bit_cast(f16x8, t);
}

DI f16x8 cvt8(const float* p) {
    float4v u = *(const float4v*)p;
    float4v w = *(const float4v*)(p + 4);
    f16x8 o;
    o[0] = (_Float16)u[0]; o[1] = (_Float16)u[1]; o[2] = (_Float16)u[2]; o[3] = (_Float16)u[3];
    o[4] = (_Float16)w[0]; o[5] = (_Float16)w[1]; o[6] = (_Float16)w[2]; o[7] = (_Float16)w[3];
    return o;
}

DI u64 pack4(float4v a) {
    f16x4 h;
    h[0] = (_Float16)a[0]; h[1] = (_Float16)a[1];
    h[2] = (_Float16)a[2]; h[3] = (_Float16)a[3];
    return __builtin_bit_cast(u64, h);
}

DI u64 ald64(const void* pp) {
    return __hip_atomic_load((const u64*)pp, __ATOMIC_RELAXED, __HIP_MEMORY_SCOPE_AGENT);
}
DI void ast64(void* pp, u64 v) {
    __hip_atomic_store((u64*)pp, v, __ATOMIC_RELAXED, __HIP_MEMORY_SCOPE_AGENT);
}
DI void ast16(void* pp, unsigned short v) {
    __hip_atomic_store((unsigned short*)pp, v, __ATOMIC_RELAXED, __HIP_MEMORY_SCOPE_AGENT);
}
DI unsigned int aldu32(const unsigned int* pp) {
    return __hip_atomic_load(pp, __ATOMIC_RELAXED, __HIP_MEMORY_SCOPE_AGENT);
}
DI void astu32(unsigned int* pp, unsigned int v) {
    __hip_atomic_store(pp, v, __ATOMIC_RELAXED, __HIP_MEMORY_SCOPE_AGENT);
}

// ---------------------------------------------------------------------------
// R18: R16 mega-kernel (8-wave WGs -- R17's 4-wave variant REGRESSED: 1
// wave/SIMD loses intra-SIMD interleave latency-hiding) + MFMA chain split.
// Change vs R16: the recurrence 4-deep dependent MFMA chain (kc=0..3 into one
// acc) is split into two independent 2-deep chains (kc 0-1 -> accL, kc 2-3 ->
// accH2) combined after the select with 4 VALU adds: removes ~2 MFMA
// latencies from every step's serial path. Producer + consumer only; helper/
// xph/out and ALL handshakes bit-identical to R16.
//   role 0 (WG  0-15): producer encL0 -> decL0 (state in registers).
//   role 1 (WG 16-31): consumer encL1 -> decL1 (y1 ring in dec).
//   role 2 (WG 32-47): Wih-helper eW1 -> dW1 (PB -> X2 ring).
//   role 3 (WG 48-63): xph (x @ eW0^T -> X1 ring), exits at NG.
//   role 4 (WG 64-79): out (y1 @ oW^T + ob -> d_out), runs NG..2NG.
// ---------------------------------------------------------------------------
__global__ __launch_bounds__(512, 1) void lstm_mega(
    const float* __restrict__ eU0, const float* __restrict__ eb0i, const float* __restrict__ eb0h,
    const float* __restrict__ dU0, const float* __restrict__ db0i, const float* __restrict__ db0h,
    const float* __restrict__ eU1, const float* __restrict__ eb1i, const float* __restrict__ eb1h,
    const float* __restrict__ dU1, const float* __restrict__ db1i, const float* __restrict__ db1h,
    const float* __restrict__ eW1, const float* __restrict__ dW1,
    const float* __restrict__ eW0, const float* __restrict__ xin,
    const float* __restrict__ oW,  const float* __restrict__ ob,
    float* __restrict__ outp,
    _Float16* __restrict__ PB,          // y0 ring  [64][RING][128] f16
    _Float16* __restrict__ X2,          // xp2 ring [64][RING][512] f16 (PERM)
    _Float16* __restrict__ X1,          // xp  ring [64][RING][512] f16 (PERM)
    _Float16* __restrict__ Y1,          // y1  ring [64][RING][128] f16
    unsigned int* __restrict__ prog,  unsigned int* __restrict__ prog2,
    unsigned int* __restrict__ prog3, unsigned int* __restrict__ prog4,
    unsigned int* __restrict__ prog5, int T)
{
    const int tid  = threadIdx.x;
    const int lane = tid & 63, w = tid >> 6;
    const int col  = lane & 15, quad = lane >> 4;
    const int b    = col & 3, s = col >> 2;
    const int role = blockIdx.x >> 4;        // 0 prod, 1 cons, 2 Wih, 3 xph, 4 out
    const int p    = blockIdx.x & 15;
    const int bglob = p * 4 + b;
    const int j    = w * 16 + s * 4 + quad;
    const int NG   = T >> 3;                 // T % 8 == 0 (T=2048)
    const int NG2  = NG * 2;
    const unsigned int T2 = (unsigned int)(2 * T);

    __shared__ alignas(16) _Float16 Hl[2 * 4 * HSTR];
    __shared__ alignas(16) _Float16 Ylh[32 * YSTR];   // helper granule stage

    unsigned int* pr  = prog  + p * 16;   // 64B stride
    unsigned int* pr2 = prog2 + p * 16;
    unsigned int* pr3 = prog3 + p * 16;
    unsigned int* pr4 = prog4 + p * 16;
    unsigned int* pr5 = prog5 + p * 16;

    if (role == 0) {
        // ================= producer: encL0 then decL0 =====================
        f16x8 af[4][4];
        float bq[4];
#pragma unroll
        for (int mt = 0; mt < 4; mt++) {
            int urow = (col & 3) * 128 + (w * 16 + mt * 4 + (col >> 2));
            const float* ur = eU0 + (size_t)urow * 128;
#pragma unroll
            for (int kc = 0; kc < 4; kc++) { af[mt][kc] = cvt8(ur + kc * 32 + quad * 8); pin(af[mt][kc]); }
        }
#pragma unroll
        for (int q = 0; q < 4; q++) bq[q] = eb0i[q * 128 + j] + eb0h[q * 128 + j];

        float c = 0.f, hv = 0.f;
        Hl[b * HSTR + j] = (_Float16)0.f;
        __syncthreads();

        const _Float16* x1b = X1 + (size_t)bglob * RING * 512 + 4 * j;
        unsigned short* pbp = (unsigned short*)PB + (size_t)bglob * RING * 128 + j;

        // pre-poll: granule-0 prefetches reach xp index 8 -> prog3 >= 16
        if (tid == 511) {
            unsigned int need = 16u; if (need > (unsigned int)T) need = (unsigned int)T;
            unsigned int psn = aldu32(pr3);
            while (psn < need) { __builtin_amdgcn_s_sleep(8); psn = aldu32(pr3); }
        }
        __syncthreads();
        f16x4 xp = __builtin_bit_cast(f16x4, ald64(x1b));   // xp(0)

        int cur = 0;
        unsigned int pf3 = 0, ps3 = 0;
        for (int g = 0; g < NG2; g++) {
            if (g == NG) {
                // phase switch: decL0 weights/biases; state (c,hv) continues.
#pragma unroll
                for (int mt = 0; mt < 4; mt++) {
                    int urow = (col & 3) * 128 + (w * 16 + mt * 4 + (col >> 2));
                    const float* ur = dU0 + (size_t)urow * 128;
#pragma unroll
                    for (int kc = 0; kc < 4; kc++) { af[mt][kc] = cvt8(ur + kc * 32 + quad * 8); pin(af[mt][kc]); }
                }
#pragma unroll
                for (int q = 0; q < 4; q++) bq[q] = db0i[q * 128 + j] + db0h[q * 128 + j];
            }
            if (g < NG) {
                // in-flight prog3 sample (checked at k==7)
                if (tid == 511 && g + 1 < NG) pf3 = aldu32(pr3);
#pragma unroll
                for (int k = 0; k < 8; k++) {
                    const int t = g * 8 + k;
                    f16x4 xpn = __builtin_bit_cast(f16x4,
                        ald64(x1b + (size_t)((t + 1) & (RING - 1)) * 512));

                    const _Float16* Hc = Hl + cur * (4 * HSTR);
                    f16x8 bf[4];
#pragma unroll
                    for (int kc = 0; kc < 4; kc++)
                        bf[kc] = *(const f16x8*)(Hc + b * HSTR + kc * 32 + quad * 8);

                    // split chains: kc 0-1 -> accL, kc 2-3 -> accH2 (2-deep each)
                    float4v accL[4] = {}, accH2[4] = {};
#pragma unroll
                    for (int mt = 0; mt < 4; mt++) {
                        accL[mt]  = __builtin_amdgcn_mfma_f32_16x16x32_f16(af[mt][0], bf[0], accL[mt], 0, 0, 0);
                        accH2[mt] = __builtin_amdgcn_mfma_f32_16x16x32_f16(af[mt][2], bf[2], accH2[mt], 0, 0, 0);
                        accL[mt]  = __builtin_amdgcn_mfma_f32_16x16x32_f16(af[mt][1], bf[1], accL[mt], 0, 0, 0);
                        accH2[mt] = __builtin_amdgcn_mfma_f32_16x16x32_f16(af[mt][3], bf[3], accH2[mt], 0, 0, 0);
                    }

                    float4v l0 = (s & 1) ? accL[1] : accL[0];
                    float4v l1 = (s & 1) ? accL[3] : accL[2];
                    float4v gL = (s & 2) ? l1 : l0;
                    float4v h0 = (s & 1) ? accH2[1] : accH2[0];
                    float4v h1 = (s & 1) ? accH2[3] : accH2[2];
                    float4v gH = (s & 2) ? h1 : h0;

                    float g0 = gL[0] + gH[0] + bq[0] + (float)xp[0];
                    float g1 = gL[1] + gH[1] + bq[1] + (float)xp[1];
                    float g2 = gL[2] + gH[2] + bq[2] + (float)xp[2];
                    float g3 = gL[3] + gH[3] + bq[3] + (float)xp[3];
                    float iv = sigf_fast(g0), fv = sigf_fast(g1);
                    float gv = tanhf_fast(g2), ov = sigf_fast(g3);
                    c  = fv * c + iv * gv;
                    hv = ov * tanhf_fast(c);

                    _Float16 hf = (_Float16)hv;
                    Hl[(cur ^ 1) * (4 * HSTR) + b * HSTR + j] = hf;
                    ast16(pbp + (size_t)(t & (RING - 1)) * 128,
                          __builtin_bit_cast(unsigned short, hf));

                    if (k == 7) {
                        // only newest {xpload, PBstore} outstanding -> y(<=8g+6) ACKed
                        asm volatile("s_waitcnt vmcnt(2)" ::: "memory");
                        if (tid == 0) astu32(pr, (unsigned int)(g * 8 + 7));
                        if (tid == 511 && g + 1 < NG) {
                            unsigned int need = (unsigned int)(8 * (g + 1) + 16);
                            if (need > (unsigned int)T) need = (unsigned int)T;
                            if (ps3 < pf3) ps3 = pf3;
                            while (ps3 < need) { __builtin_amdgcn_s_sleep(2); ps3 = aldu32(pr3); }
                        }
                    }
                    lds_barrier();
                    xp = xpn;
                    cur ^= 1;
                }
            } else {
#pragma unroll
                for (int k = 0; k < 8; k++) {
                    const int t = g * 8 + k;

                    const _Float16* Hc = Hl + cur * (4 * HSTR);
                    f16x8 bf[4];
#pragma unroll
                    for (int kc = 0; kc < 4; kc++)
                        bf[kc] = *(const f16x8*)(Hc + b * HSTR + kc * 32 + quad * 8);

                    float4v accL[4] = {}, accH2[4] = {};
#pragma unroll
                    for (int mt = 0; mt < 4; mt++) {
                        accL[mt]  = __builtin_amdgcn_mfma_f32_16x16x32_f16(af[mt][0], bf[0], accL[mt], 0, 0, 0);
                        accH2[mt] = __builtin_amdgcn_mfma_f32_16x16x32_f16(af[mt][2], bf[2], accH2[mt], 0, 0, 0);
                        accL[mt]  = __builtin_amdgcn_mfma_f32_16x16x32_f16(af[mt][1], bf[1], accL[mt], 0, 0, 0);
                        accH2[mt] = __builtin_amdgcn_mfma_f32_16x16x32_f16(af[mt][3], bf[3], accH2[mt], 0, 0, 0);
                    }

                    float4v l0 = (s & 1) ? accL[1] : accL[0];
                    float4v l1 = (s & 1) ? accL[3] : accL[2];
                    float4v gL = (s & 2) ? l1 : l0;
                    float4v h0 = (s & 1) ? accH2[1] : accH2[0];
                    float4v h1 = (s & 1) ? accH2[3] : accH2[2];
                    float4v gH = (s & 2) ? h1 : h0;

                    float g0 = gL[0] + gH[0] + bq[0], g1 = gL[1] + gH[1] + bq[1];
                    float g2 = gL[2] + gH[2] + bq[2], g3 = gL[3] + gH[3] + bq[3];
                    float iv = sigf_fast(g0), fv = sigf_fast(g1);
                    float gv = tanhf_fast(g2), ov = sigf_fast(g3);
                    c  = fv * c + iv * gv;
                    hv = ov * tanhf_fast(c);

                    _Float16 hf = (_Float16)hv;
                    Hl[(cur ^ 1) * (4 * HSTR) + b * HSTR + j] = hf;
                    ast16(pbp + (size_t)(t & (RING - 1)) * 128,
                          __builtin_bit_cast(unsigned short, hf));

                    if (k == 7) {
                        asm volatile("s_waitcnt vmcnt(1)" ::: "memory");
                        if (tid == 0) astu32(pr, (unsigned int)(g * 8 + 7));
                    }
                    lds_barrier();
                    cur ^= 1;
                }
            }
        }
        asm volatile("s_waitcnt vmcnt(0)" ::: "memory");
        __syncthreads();
        if (tid == 0) astu32(pr, T2);
    } else if (role == 1) {
        // ================= consumer: encL1 then decL1 =====================
        f16x8 afH[4][4];
        float bq[4];
#pragma unroll
        for (int mt = 0; mt < 4; mt++) {
            int urow = (col & 3) * 128 + (w * 16 + mt * 4 + (col >> 2));
            const float* ur = eU1 + (size_t)urow * 128;
#pragma unroll
            for (int kc = 0; kc < 4; kc++) { afH[mt][kc] = cvt8(ur + kc * 32 + quad * 8); pin(afH[mt][kc]); }
        }
#pragma unroll
        for (int q = 0; q < 4; q++) bq[q] = eb1i[q * 128 + j] + eb1h[q * 128 + j];

        float c = 0.f, hv = 0.f;
        Hl[b * HSTR + j] = (_Float16)0.f;

        // pre-poll: granule-0 prefetches reach xp2 index 8 -> prog2 >= 9
        if (tid == 511) {
            unsigned int need = 9u; if (need > T2) need = T2;
            unsigned int psn = aldu32(pr2);
            while (psn < need) { __builtin_amdgcn_s_sleep(8); psn = aldu32(pr2); }
        }
        __syncthreads();

        const _Float16* x2b = X2 + (size_t)bglob * RING * 512 + 4 * j;
        unsigned short* y1p = (unsigned short*)Y1 + (size_t)bglob * RING * 128 + j;
        f16x4 xp = __builtin_bit_cast(f16x4, ald64(x2b));   // xp2(0)

        int cur = 0;
        unsigned int pf2 = 0, ps2 = 0, pf5 = 0, ps5 = 0;
        for (int g = 0; g < NG2; g++) {
            if (g == NG) {
                // phase switch: decL1 weights/biases; state continues.
#pragma unroll
                for (int mt = 0; mt < 4; mt++) {
                    int urow = (col & 3) * 128 + (w * 16 + mt * 4 + (col >> 2));
                    const float* ur = dU1 + (size_t)urow * 128;
#pragma unroll
                    for (int kc = 0; kc < 4; kc++) { afH[mt][kc] = cvt8(ur + kc * 32 + quad * 8); pin(afH[mt][kc]); }
                }
#pragma unroll
                for (int q = 0; q < 4; q++) bq[q] = db1i[q * 128 + j] + db1h[q * 128 + j];
            }
            // in-flight samples (checked at k==7)
            if (tid == 511) {
                if (g + 1 < NG2) pf2 = aldu32(pr2);
                if (g + 1 >= NG + 32 && g + 1 < NG2) pf5 = aldu32(pr5);
            }
            const bool isDec = (g >= NG);
#pragma unroll
            for (int k = 0; k < 8; k++) {
                const int t = g * 8 + k;
                f16x4 xpn = __builtin_bit_cast(f16x4,
                    ald64(x2b + (size_t)((t + 1) & (RING - 1)) * 512));

                const _Float16* Hc = Hl + cur * (4 * HSTR);
                f16x8 bf[4];
#pragma unroll
                for (int kc = 0; kc < 4; kc++)
                    bf[kc] = *(const f16x8*)(Hc + b * HSTR + kc * 32 + quad * 8);

                float4v accL[4] = {}, accH2[4] = {};
#pragma unroll
                for (int mt = 0; mt < 4; mt++) {
                    accL[mt]  = __builtin_amdgcn_mfma_f32_16x16x32_f16(afH[mt][0], bf[0], accL[mt], 0, 0, 0);
                    accH2[mt] = __builtin_amdgcn_mfma_f32_16x16x32_f16(afH[mt][2], bf[2], accH2[mt], 0, 0, 0);
                    accL[mt]  = __builtin_amdgcn_mfma_f32_16x16x32_f16(afH[mt][1], bf[1], accL[mt], 0, 0, 0);
                    accH2[mt] = __builtin_amdgcn_mfma_f32_16x16x32_f16(afH[mt][3], bf[3], accH2[mt], 0, 0, 0);
                }

                float4v l0 = (s & 1) ? accL[1] : accL[0];
                float4v l1 = (s & 1) ? accL[3] : accL[2];
                float4v gL = (s & 2) ? l1 : l0;
                float4v h0 = (s & 1) ? accH2[1] : accH2[0];
                float4v h1 = (s & 1) ? accH2[3] : accH2[2];
                float4v gH = (s & 2) ? h1 : h0;

                float g0 = gL[0] + gH[0] + bq[0] + (float)xp[0];
                float g1 = gL[1] + gH[1] + bq[1] + (float)xp[1];
                float g2 = gL[2] + gH[2] + bq[2] + (float)xp[2];
                float g3 = gL[3] + gH[3] + bq[3] + (float)xp[3];
                float iv = sigf_fast(g0), fv = sigf_fast(g1);
                float gv = tanhf_fast(g2), ov = sigf_fast(g3);
                c  = fv * c + iv * gv;
                hv = ov * tanhf_fast(c);

                _Float16 hf = (_Float16)hv;
                Hl[(cur ^ 1) * (4 * HSTR) + b * HSTR + j] = hf;
                if (isDec)
                    ast16(y1p + (size_t)(t & (RING - 1)) * 128,
                          __builtin_bit_cast(unsigned short, hf));

                if (k == 7) {
                    if (isDec) {
                        // y1(<=8g+6) ACKed (newest {xp2load, y1store} remain)
                        asm volatile("s_waitcnt vmcnt(2)" ::: "memory");
                        if (tid == 0) astu32(pr4, (unsigned int)(g * 8 + 7));
                    }
                    if (tid == 511 && g + 1 < NG2) {
                        unsigned int need = (unsigned int)(8 * (g + 1) + 9);
                        if (need > T2) need = T2;
                        if (ps2 < pf2) ps2 = pf2;
                        while (ps2 < need) { __builtin_amdgcn_s_sleep(2); ps2 = aldu32(pr2); }
                        if (isDec && g + 1 >= NG + 32) {
                            // y1-ring back-gate: out must have staged g+1-32
                            unsigned int need5 = (unsigned int)(8 * (g + 1 - 32) + 8);
                            if (ps5 < pf5) ps5 = pf5;
                            while (ps5 < need5) { __builtin_amdgcn_s_sleep(2); ps5 = aldu32(pr5); }
                        }
                    }
                }
                lds_barrier();
                xp = xpn;
                cur ^= 1;
            }
        }
        asm volatile("s_waitcnt vmcnt(0)" ::: "memory");
        __syncthreads();
        if (tid == 0) astu32(pr4, T2);
    } else if (role == 2) {
        // ========== Wih-helper: XP2 = W @ y0 (swapped-operand), 2T ========
        f16x8 bw[4][4];
#pragma unroll
        for (int nt = 0; nt < 4; nt++) {
            int n = (w * 4 + nt) * 16 + col;
            int wrow = (n & 3) * 128 + (n >> 2);
            const float* Wr = eW1 + (size_t)wrow * 128;
#pragma unroll
            for (int kc = 0; kc < 4; kc++) { bw[nt][kc] = cvt8(Wr + kc * 32 + quad * 8); pin(bw[nt][kc]); }
        }

        const int lrow = tid >> 4, lchunk = tid & 15;
        const int lb = lrow & 3, ltr = lrow >> 2;

        for (int g = 0; g < NG2; g++) {
            if (g == NG) {
#pragma unroll
                for (int nt = 0; nt < 4; nt++) {
                    int n = (w * 4 + nt) * 16 + col;
                    int wrow = (n & 3) * 128 + (n >> 2);
                    const float* Wr = dW1 + (size_t)wrow * 128;
#pragma unroll
                    for (int kc = 0; kc < 4; kc++) { bw[nt][kc] = cvt8(Wr + kc * 32 + quad * 8); pin(bw[nt][kc]); }
                }
            }
            if (tid == 0) {
                unsigned int need = (unsigned int)(g * 8 + 8);
                unsigned int psn = aldu32(pr);
                while (psn < need) { __builtin_amdgcn_s_sleep(4); psn = aldu32(pr); }
            }
            __syncthreads();
            {
                int slot = (g * 8 + ltr) & (RING - 1);
                const char* srcp = (const char*)(PB + ((size_t)(p * 4 + lb) * RING + slot) * 128 + lchunk * 8);
                u64 a0 = ald64(srcp);
                u64 a1 = ald64(srcp + 8);
                char* dst = (char*)&Ylh[lrow * YSTR + lchunk * 8];
                *(u64*)dst = a0;
                *(u64*)(dst + 8) = a1;
            }
            lds_barrier();

            float4v acc[2][4] = {};
#pragma unroll
            for (int kc = 0; kc < 4; kc++) {
                f16x8 y0  = *(const f16x8*)&Ylh[col * YSTR + kc * 32 + quad * 8];
                f16x8 y1t = *(const f16x8*)&Ylh[(16 + col) * YSTR + kc * 32 + quad * 8];
#pragma unroll
                for (int nt = 0; nt < 4; nt++) {
                    acc[0][nt] = __builtin_amdgcn_mfma_f32_16x16x32_f16(bw[nt][kc], y0,  acc[0][nt], 0, 0, 0);
                    acc[1][nt] = __builtin_amdgcn_mfma_f32_16x16x32_f16(bw[nt][kc], y1t, acc[1][nt], 0, 0, 0);
                }
            }
            {
                const int bb = col & 3;
#pragma unroll
                for (int mt = 0; mt < 2; mt++) {
                    int trow = mt * 4 + (col >> 2);
                    int slot = (g * 8 + trow) & (RING - 1);
                    _Float16* dst = X2 + ((size_t)(p * 4 + bb) * RING + slot) * 512 + (w * 4) * 16 + quad * 4;
#pragma unroll
                    for (int nt = 0; nt < 4; nt++)
                        ast64(dst + nt * 16, pack4(acc[mt][nt]));
                }
            }
            asm volatile("s_waitcnt vmcnt(0)" ::: "memory");
            __syncthreads();
            if (tid == 0) astu32(pr2, (unsigned int)(g * 8 + 8));
        }
    } else if (role == 3) {
        // ========== xph: XP = x @ eW0^T (PERM, swapped) -> X1, exits at NG =
        f16x8 bw[4][4];
#pragma unroll
        for (int nt = 0; nt < 4; nt++) {
            int n = (w * 4 + nt) * 16 + col;
            int wrow = (n & 3) * 128 + (n >> 2);
            const float* Wr = eW0 + (size_t)wrow * 128;
#pragma unroll
            for (int kc = 0; kc < 4; kc++) { bw[nt][kc] = cvt8(Wr + kc * 32 + quad * 8); pin(bw[nt][kc]); }
        }

        const int lrow = tid >> 4, lchunk = tid & 15;
        const int lb = lrow & 3, ltr = lrow >> 2;
        const float* xsrc = xin + (size_t)(p * 4 + lb) * T * 128 + lchunk * 8;

        for (int g = 0; g < NG; g++) {
            // lap-gate: don't overwrite xp slots the producer hasn't read.
            if (g >= 32 && tid == 0) {
                unsigned int need = (unsigned int)(8 * (g - 32));
                unsigned int psn = aldu32(pr);
                while (psn < need) { __builtin_amdgcn_s_sleep(4); psn = aldu32(pr); }
            }
            __syncthreads();
            {   // stage x granule, f32 -> f16
                f16x8 xv = cvt8(xsrc + (size_t)(g * 8 + ltr) * 128);
                u64p w2 = __builtin_bit_cast(u64p, xv);
                char* dst = (char*)&Ylh[lrow * YSTR + lchunk * 8];
                *(u64*)dst = w2.a;
                *(u64*)(dst + 8) = w2.b;
            }
            lds_barrier();

            float4v acc[2][4] = {};
#pragma unroll
            for (int kc = 0; kc < 4; kc++) {
                f16x8 y0  = *(const f16x8*)&Ylh[col * YSTR + kc * 32 + quad * 8];
                f16x8 y1t = *(const f16x8*)&Ylh[(16 + col) * YSTR + kc * 32 + quad * 8];
#pragma unroll
                for (int nt = 0; nt < 4; nt++) {
                    acc[0][nt] = __builtin_amdgcn_mfma_f32_16x16x32_f16(bw[nt][kc], y0,  acc[0][nt], 0, 0, 0);
                    acc[1][nt] = __builtin_amdgcn_mfma_f32_16x16x32_f16(bw[nt][kc], y1t, acc[1][nt], 0, 0, 0);
                }
            }
            {
                const int bb = col & 3;
#pragma unroll
                for (int mt = 0; mt < 2; mt++) {
                    int trow = mt * 4 + (col >> 2);
                    int slot = (g * 8 + trow) & (RING - 1);
                    _Float16* dst = X1 + ((size_t)(p * 4 + bb) * RING + slot) * 512 + (w * 4) * 16 + quad * 4;
#pragma unroll
                    for (int nt = 0; nt < 4; nt++)
                        ast64(dst + nt * 16, pack4(acc[mt][nt]));
                }
            }
            asm volatile("s_waitcnt vmcnt(0)" ::: "memory");
            __syncthreads();
            if (tid == 0) astu32(pr3, (unsigned int)(g * 8 + 8));
        }
    } else {
        // ========== out: d_out = y1 @ oW^T + ob; runs g = NG..2NG-1 =======
        f16x8 bo[4];
#pragma unroll
        for (int kc = 0; kc < 4; kc++) { bo[kc] = cvt8(oW + (size_t)(w * 16 + col) * 128 + kc * 32 + quad * 8); pin(bo[kc]); }
        float4v bv4 = *(const float4v*)(ob + w * 16 + quad * 4);

        const int lrow = tid >> 4, lchunk = tid & 15;
        const int lb = lrow & 3, ltr = lrow >> 2;

        for (int gg = 0; gg < NG; gg++) {
            const int g = NG + gg;
            if (tid == 0) {
                unsigned int need = (unsigned int)(g * 8 + 8);
                unsigned int psn = aldu32(pr4);
                while (psn < need) { __builtin_amdgcn_s_sleep(4); psn = aldu32(pr4); }
            }
            __syncthreads();   // also fences prior granule's Ylh reads
            {
                int slot = (g * 8 + ltr) & (RING - 1);
                const char* srcp = (const char*)(Y1 + ((size_t)(p * 4 + lb) * RING + slot) * 128 + lchunk * 8);
                u64 a0 = ald64(srcp);
                u64 a1 = ald64(srcp + 8);
                char* dst = (char*)&Ylh[lrow * YSTR + lchunk * 8];
                *(u64*)dst = a0;
                *(u64*)(dst + 8) = a1;
            }
            lds_barrier();
            // release consumed-progress: granule g's ring slots fully staged.
            if (tid == 0) astu32(pr5, (unsigned int)(g * 8 + 8));

            float4v acc[2] = {};
#pragma unroll
            for (int kc = 0; kc < 4; kc++) {
                f16x8 y0  = *(const f16x8*)&Ylh[col * YSTR + kc * 32 + quad * 8];
                f16x8 y1t = *(const f16x8*)&Ylh[(16 + col) * YSTR + kc * 32 + quad * 8];
                acc[0] = __builtin_amdgcn_mfma_f32_16x16x32_f16(bo[kc], y0,  acc[0], 0, 0, 0);
                acc[1] = __builtin_amdgcn_mfma_f32_16x16x32_f16(bo[kc], y1t, acc[1], 0, 0, 0);
            }
            {
                const int bb = col & 3;
#pragma unroll
                for (int mt = 0; mt < 2; mt++) {
                    int trow = mt * 4 + (col >> 2);
                    float4v v = acc[mt];
                    v[0] += bv4[0]; v[1] += bv4[1]; v[2] += bv4[2]; v[3] += bv4[3];
                    *(float4v*)(outp + ((size_t)(p * 4 + bb) * T + gg * 8 + trow) * 128 + w * 16 + quad * 4) = v;
                }
            }
        }
    }
}

// ---------------------------------------------------------------------------
// Host: memset + ONE launch (80 WGs x 512 threads).
//   ws map: X1 [0,16M) | X2 [16,32M) | PB [32,36M) | Y1 [36,40M) | prog @40M
// ---------------------------------------------------------------------------
extern "C" void kernel_launch(void* const* d_in, const int* in_sizes, int n_in,
                              void* d_out, int out_size, void* d_ws, size_t ws_size,
                              hipStream_t stream)
{
    const float* x    = (const float*)d_in[0];
    const float* eW0  = (const float*)d_in[1];
    const float* eU0  = (const float*)d_in[2];
    const float* eb0i = (const float*)d_in[3];
    const float* eb0h = (const float*)d_in[4];
    const float* eW1  = (const float*)d_in[5];
    const float* eU1  = (const float*)d_in[6];
    const float* eb1i = (const float*)d_in[7];
    const float* eb1h = (const float*)d_in[8];
    const float* dU0  = (const float*)d_in[10];
    const float* db0i = (const float*)d_in[11];
    const float* db0h = (const float*)d_in[12];
    const float* dW1  = (const float*)d_in[13];
    const float* dU1  = (const float*)d_in[14];
    const float* db1i = (const float*)d_in[15];
    const float* db1h = (const float*)d_in[16];
    const float* oW   = (const float*)d_in[17];
    const float* ob   = (const float*)d_in[18];

    char* ws = (char*)d_ws;
    _Float16* X1 = (_Float16*)(ws);                  // 16MB
    _Float16* X2 = (_Float16*)(ws + (16u << 20));    // 16MB
    _Float16* PB = (_Float16*)(ws + (32u << 20));    //  4MB
    _Float16* Y1 = (_Float16*)(ws + (36u << 20));    //  4MB
    unsigned int* pg = (unsigned int*)(ws + (40u << 20));

    hipMemsetAsync((void*)pg, 0, 8192, stream);

    lstm_mega<<<dim3(80), dim3(512), 0, stream>>>(
        eU0, eb0i, eb0h, dU0, db0i, db0h,
        eU1, eb1i, eb1h, dU1, db1i, db1h,
        eW1, dW1, eW0, x, oW, ob, (float*)d_out,
        PB, X2, X1, Y1,
        pg, pg + 256, pg + 512, pg + 768, pg + 1024, Tlen);
}

// Round 11
// 2277.228 us; speedup vs baseline: 1.1481x; 1.0855x over previous
//
#include <hip/hip_runtime.h>
#include <cstdint>
#include <cstddef>

typedef float    float4v __attribute__((ext_vector_type(4)));
typedef _Float16 f16x4   __attribute__((ext_vector_type(4)));
typedef _Float16 f16x8   __attribute__((ext_vector_type(8)));
typedef unsigned long long u64;
struct u64p { u64 a, b; };

#define DI __device__ __forceinline__

static const int Bsz = 64, Tlen = 2048, Hd = 128;
static const int HSTR = 144;   // H row stride (f16): 0 bank conflicts (R7)
static const int RING = 256;   // ring length (steps)
static const int YSTR = 136;   // helper LDS row stride (f16)

DI float sigf_fast(float x) {
    float e = __builtin_amdgcn_exp2f(-1.442695041f * x);
    return __builtin_amdgcn_rcpf(1.f + e);
}
DI float tanhf_fast(float x) {
    float e = __builtin_amdgcn_exp2f(-2.885390082f * x);
    return 2.f * __builtin_amdgcn_rcpf(1.f + e) - 1.f;
}

DI void lds_barrier() {
    asm volatile("s_waitcnt lgkmcnt(0)\n\ts_barrier" ::: "memory");
}

DI void pin(f16x8& v) {
    float4v t = __builtin_bit_cast(float4v, v);
    asm volatile("" : "+v"(t));
    v = __builtin_bit_cast(f16x8, t);
}

DI f16x8 cvt8(const float* p) {
    float4v u = *(const float4v*)p;
    float4v w = *(const float4v*)(p + 4);
    f16x8 o;
    o[0] = (_Float16)u[0]; o[1] = (_Float16)u[1]; o[2] = (_Float16)u[2]; o[3] = (_Float16)u[3];
    o[4] = (_Float16)w[0]; o[5] = (_Float16)w[1]; o[6] = (_Float16)w[2]; o[7] = (_Float16)w[3];
    return o;
}

DI u64 pack4(float4v a) {
    f16x4 h;
    h[0] = (_Float16)a[0]; h[1] = (_Float16)a[1];
    h[2] = (_Float16)a[2]; h[3] = (_Float16)a[3];
    return __builtin_bit_cast(u64, h);
}

DI u64 ald64(const void* pp) {
    return __hip_atomic_load((const u64*)pp, __ATOMIC_RELAXED, __HIP_MEMORY_SCOPE_AGENT);
}
DI void ast64(void* pp, u64 v) {
    __hip_atomic_store((u64*)pp, v, __ATOMIC_RELAXED, __HIP_MEMORY_SCOPE_AGENT);
}
DI void ast16(void* pp, unsigned short v) {
    __hip_atomic_store((unsigned short*)pp, v, __ATOMIC_RELAXED, __HIP_MEMORY_SCOPE_AGENT);
}
DI unsigned int aldu32(const unsigned int* pp) {
    return __hip_atomic_load(pp, __ATOMIC_RELAXED, __HIP_MEMORY_SCOPE_AGENT);
}
DI void astu32(unsigned int* pp, unsigned int v) {
    __hip_atomic_store(pp, v, __ATOMIC_RELAXED, __HIP_MEMORY_SCOPE_AGENT);
}

// ---------------------------------------------------------------------------
// R19 = R16 verified body (REVERT of R18's chain split, which regressed:
// step is NOT MFMA-latency bound) + two micro-cuts on coherence latency:
//   (1) 2-deep xp ring prefetch (load t+2 during step t): in-flight window
//       ~1.1us >> coherence-point latency; VMEM op count/order per step
//       unchanged -> all vmcnt counts + poll thresholds unchanged.
//   (2) publish agent-store issued BEFORE the Hl ds_write: store starts its
//       coherence trip earlier, shaving k==7 vmcnt(2) exposure.
// Roles/handshakes identical to R16:
//   role 0 (WG  0-15): producer encL0 -> decL0 (state in registers).
//   role 1 (WG 16-31): consumer encL1 -> decL1 (y1 ring in dec).
//   role 2 (WG 32-47): Wih-helper eW1 -> dW1 (PB -> X2 ring).
//   role 3 (WG 48-63): xph (x @ eW0^T -> X1 ring), exits at NG.
//   role 4 (WG 64-79): out (y1 @ oW^T + ob -> d_out), runs NG..2NG.
// Step-latency floor note: 6 structural probes (R11/R12/R15/R17/R18 + poll
// restructures) pin the recurrence at ~568ns/step = {gate VALU -> LDS
// h-broadcast -> WG barrier -> ds_read -> 16 MFMA}; phase-staggered wave
// streams would need split barriers, which CDNA4/HIP does not expose.
// ---------------------------------------------------------------------------
__global__ __launch_bounds__(512, 1) void lstm_mega(
    const float* __restrict__ eU0, const float* __restrict__ eb0i, const float* __restrict__ eb0h,
    const float* __restrict__ dU0, const float* __restrict__ db0i, const float* __restrict__ db0h,
    const float* __restrict__ eU1, const float* __restrict__ eb1i, const float* __restrict__ eb1h,
    const float* __restrict__ dU1, const float* __restrict__ db1i, const float* __restrict__ db1h,
    const float* __restrict__ eW1, const float* __restrict__ dW1,
    const float* __restrict__ eW0, const float* __restrict__ xin,
    const float* __restrict__ oW,  const float* __restrict__ ob,
    float* __restrict__ outp,
    _Float16* __restrict__ PB,          // y0 ring  [64][RING][128] f16
    _Float16* __restrict__ X2,          // xp2 ring [64][RING][512] f16 (PERM)
    _Float16* __restrict__ X1,          // xp  ring [64][RING][512] f16 (PERM)
    _Float16* __restrict__ Y1,          // y1  ring [64][RING][128] f16
    unsigned int* __restrict__ prog,  unsigned int* __restrict__ prog2,
    unsigned int* __restrict__ prog3, unsigned int* __restrict__ prog4,
    unsigned int* __restrict__ prog5, int T)
{
    const int tid  = threadIdx.x;
    const int lane = tid & 63, w = tid >> 6;
    const int col  = lane & 15, quad = lane >> 4;
    const int b    = col & 3, s = col >> 2;
    const int role = blockIdx.x >> 4;        // 0 prod, 1 cons, 2 Wih, 3 xph, 4 out
    const int p    = blockIdx.x & 15;
    const int bglob = p * 4 + b;
    const int j    = w * 16 + s * 4 + quad;
    const int NG   = T >> 3;                 // T % 8 == 0 (T=2048)
    const int NG2  = NG * 2;
    const unsigned int T2 = (unsigned int)(2 * T);

    __shared__ alignas(16) _Float16 Hl[2 * 4 * HSTR];
    __shared__ alignas(16) _Float16 Ylh[32 * YSTR];   // helper granule stage

    unsigned int* pr  = prog  + p * 16;   // 64B stride
    unsigned int* pr2 = prog2 + p * 16;
    unsigned int* pr3 = prog3 + p * 16;
    unsigned int* pr4 = prog4 + p * 16;
    unsigned int* pr5 = prog5 + p * 16;

    if (role == 0) {
        // ================= producer: encL0 then decL0 =====================
        f16x8 af[4][4];
        float bq[4];
#pragma unroll
        for (int mt = 0; mt < 4; mt++) {
            int urow = (col & 3) * 128 + (w * 16 + mt * 4 + (col >> 2));
            const float* ur = eU0 + (size_t)urow * 128;
#pragma unroll
            for (int kc = 0; kc < 4; kc++) { af[mt][kc] = cvt8(ur + kc * 32 + quad * 8); pin(af[mt][kc]); }
        }
#pragma unroll
        for (int q = 0; q < 4; q++) bq[q] = eb0i[q * 128 + j] + eb0h[q * 128 + j];

        float c = 0.f, hv = 0.f;
        Hl[b * HSTR + j] = (_Float16)0.f;
        __syncthreads();

        const _Float16* x1b = X1 + (size_t)bglob * RING * 512 + 4 * j;
        unsigned short* pbp = (unsigned short*)PB + (size_t)bglob * RING * 128 + j;

        // pre-poll: granule-0 prefetches reach xp index 9 (2-deep) -> prog3 >= 16
        if (tid == 511) {
            unsigned int need = 16u; if (need > (unsigned int)T) need = (unsigned int)T;
            unsigned int psn = aldu32(pr3);
            while (psn < need) { __builtin_amdgcn_s_sleep(8); psn = aldu32(pr3); }
        }
        __syncthreads();
        f16x4 xp  = __builtin_bit_cast(f16x4, ald64(x1b));          // xp(0)
        f16x4 xp1 = __builtin_bit_cast(f16x4, ald64(x1b + 512));    // xp(1)

        int cur = 0;
        unsigned int pf3 = 0, ps3 = 0;
        for (int g = 0; g < NG2; g++) {
            if (g == NG) {
                // phase switch: decL0 weights/biases; state (c,hv) continues.
#pragma unroll
                for (int mt = 0; mt < 4; mt++) {
                    int urow = (col & 3) * 128 + (w * 16 + mt * 4 + (col >> 2));
                    const float* ur = dU0 + (size_t)urow * 128;
#pragma unroll
                    for (int kc = 0; kc < 4; kc++) { af[mt][kc] = cvt8(ur + kc * 32 + quad * 8); pin(af[mt][kc]); }
                }
#pragma unroll
                for (int q = 0; q < 4; q++) bq[q] = db0i[q * 128 + j] + db0h[q * 128 + j];
            }
            if (g < NG) {
                // in-flight prog3 sample (checked at k==7)
                if (tid == 511 && g + 1 < NG) pf3 = aldu32(pr3);
#pragma unroll
                for (int k = 0; k < 8; k++) {
                    const int t = g * 8 + k;
                    // 2-deep prefetch: load xp(t+2); in flight ~2 steps.
                    f16x4 xpn = __builtin_bit_cast(f16x4,
                        ald64(x1b + (size_t)((t + 2) & (RING - 1)) * 512));

                    const _Float16* Hc = Hl + cur * (4 * HSTR);
                    f16x8 bf[4];
#pragma unroll
                    for (int kc = 0; kc < 4; kc++)
                        bf[kc] = *(const f16x8*)(Hc + b * HSTR + kc * 32 + quad * 8);

                    float4v acc[4] = {};
#pragma unroll
                    for (int kc = 0; kc < 4; kc++)
#pragma unroll
                        for (int mt = 0; mt < 4; mt++)
                            acc[mt] = __builtin_amdgcn_mfma_f32_16x16x32_f16(af[mt][kc], bf[kc], acc[mt], 0, 0, 0);

                    float4v t0 = (s & 1) ? acc[1] : acc[0];
                    float4v t1 = (s & 1) ? acc[3] : acc[2];
                    float4v gg = (s & 2) ? t1 : t0;

                    float g0 = gg[0] + bq[0] + (float)xp[0], g1 = gg[1] + bq[1] + (float)xp[1];
                    float g2 = gg[2] + bq[2] + (float)xp[2], g3 = gg[3] + bq[3] + (float)xp[3];
                    float iv = sigf_fast(g0), fv = sigf_fast(g1);
                    float gv = tanhf_fast(g2), ov = sigf_fast(g3);
                    c  = fv * c + iv * gv;
                    hv = ov * tanhf_fast(c);

                    _Float16 hf = (_Float16)hv;
                    // publish FIRST (store starts coherence trip early)
                    ast16(pbp + (size_t)(t & (RING - 1)) * 128,
                          __builtin_bit_cast(unsigned short, hf));
                    Hl[(cur ^ 1) * (4 * HSTR) + b * HSTR + j] = hf;

                    if (k == 7) {
                        // only newest {xpload, PBstore} outstanding -> y(<=8g+6) ACKed
                        asm volatile("s_waitcnt vmcnt(2)" ::: "memory");
                        if (tid == 0) astu32(pr, (unsigned int)(g * 8 + 7));
                        if (tid == 511 && g + 1 < NG) {
                            unsigned int need = (unsigned int)(8 * (g + 1) + 16);
                            if (need > (unsigned int)T) need = (unsigned int)T;
                            if (ps3 < pf3) ps3 = pf3;
                            while (ps3 < need) { __builtin_amdgcn_s_sleep(2); ps3 = aldu32(pr3); }
                        }
                    }
                    lds_barrier();
                    xp = xp1; xp1 = xpn;
                    cur ^= 1;
                }
            } else {
#pragma unroll
                for (int k = 0; k < 8; k++) {
                    const int t = g * 8 + k;

                    const _Float16* Hc = Hl + cur * (4 * HSTR);
                    f16x8 bf[4];
#pragma unroll
                    for (int kc = 0; kc < 4; kc++)
                        bf[kc] = *(const f16x8*)(Hc + b * HSTR + kc * 32 + quad * 8);

                    float4v acc[4] = {};
#pragma unroll
                    for (int kc = 0; kc < 4; kc++)
#pragma unroll
                        for (int mt = 0; mt < 4; mt++)
                            acc[mt] = __builtin_amdgcn_mfma_f32_16x16x32_f16(af[mt][kc], bf[kc], acc[mt], 0, 0, 0);

                    float4v t0 = (s & 1) ? acc[1] : acc[0];
                    float4v t1 = (s & 1) ? acc[3] : acc[2];
                    float4v gg = (s & 2) ? t1 : t0;

                    float g0 = gg[0] + bq[0], g1 = gg[1] + bq[1];
                    float g2 = gg[2] + bq[2], g3 = gg[3] + bq[3];
                    float iv = sigf_fast(g0), fv = sigf_fast(g1);
                    float gv = tanhf_fast(g2), ov = sigf_fast(g3);
                    c  = fv * c + iv * gv;
                    hv = ov * tanhf_fast(c);

                    _Float16 hf = (_Float16)hv;
                    ast16(pbp + (size_t)(t & (RING - 1)) * 128,
                          __builtin_bit_cast(unsigned short, hf));
                    Hl[(cur ^ 1) * (4 * HSTR) + b * HSTR + j] = hf;

                    if (k == 7) {
                        asm volatile("s_waitcnt vmcnt(1)" ::: "memory");
                        if (tid == 0) astu32(pr, (unsigned int)(g * 8 + 7));
                    }
                    lds_barrier();
                    cur ^= 1;
                }
            }
        }
        asm volatile("s_waitcnt vmcnt(0)" ::: "memory");
        __syncthreads();
        if (tid == 0) astu32(pr, T2);
    } else if (role == 1) {
        // ================= consumer: encL1 then decL1 =====================
        f16x8 afH[4][4];
        float bq[4];
#pragma unroll
        for (int mt = 0; mt < 4; mt++) {
            int urow = (col & 3) * 128 + (w * 16 + mt * 4 + (col >> 2));
            const float* ur = eU1 + (size_t)urow * 128;
#pragma unroll
            for (int kc = 0; kc < 4; kc++) { afH[mt][kc] = cvt8(ur + kc * 32 + quad * 8); pin(afH[mt][kc]); }
        }
#pragma unroll
        for (int q = 0; q < 4; q++) bq[q] = eb1i[q * 128 + j] + eb1h[q * 128 + j];

        float c = 0.f, hv = 0.f;
        Hl[b * HSTR + j] = (_Float16)0.f;

        // pre-poll: granule-0 prefetches reach xp2 index 9 (2-deep) -> prog2 >= 10
        if (tid == 511) {
            unsigned int need = 10u; if (need > T2) need = T2;
            unsigned int psn = aldu32(pr2);
            while (psn < need) { __builtin_amdgcn_s_sleep(8); psn = aldu32(pr2); }
        }
        __syncthreads();

        const _Float16* x2b = X2 + (size_t)bglob * RING * 512 + 4 * j;
        unsigned short* y1p = (unsigned short*)Y1 + (size_t)bglob * RING * 128 + j;
        f16x4 xp  = __builtin_bit_cast(f16x4, ald64(x2b));          // xp2(0)
        f16x4 xp1 = __builtin_bit_cast(f16x4, ald64(x2b + 512));    // xp2(1)

        int cur = 0;
        unsigned int pf2 = 0, ps2 = 0, pf5 = 0, ps5 = 0;
        for (int g = 0; g < NG2; g++) {
            if (g == NG) {
                // phase switch: decL1 weights/biases; state continues.
#pragma unroll
                for (int mt = 0; mt < 4; mt++) {
                    int urow = (col & 3) * 128 + (w * 16 + mt * 4 + (col >> 2));
                    const float* ur = dU1 + (size_t)urow * 128;
#pragma unroll
                    for (int kc = 0; kc < 4; kc++) { afH[mt][kc] = cvt8(ur + kc * 32 + quad * 8); pin(afH[mt][kc]); }
                }
#pragma unroll
                for (int q = 0; q < 4; q++) bq[q] = db1i[q * 128 + j] + db1h[q * 128 + j];
            }
            // in-flight samples (checked at k==7)
            if (tid == 511) {
                if (g + 1 < NG2) pf2 = aldu32(pr2);
                if (g + 1 >= NG + 32 && g + 1 < NG2) pf5 = aldu32(pr5);
            }
            if (g < NG) {
#pragma unroll
                for (int k = 0; k < 8; k++) {
                    const int t = g * 8 + k;
                    f16x4 xpn = __builtin_bit_cast(f16x4,
                        ald64(x2b + (size_t)((t + 2) & (RING - 1)) * 512));

                    const _Float16* Hc = Hl + cur * (4 * HSTR);
                    f16x8 bf[4];
#pragma unroll
                    for (int kc = 0; kc < 4; kc++)
                        bf[kc] = *(const f16x8*)(Hc + b * HSTR + kc * 32 + quad * 8);

                    float4v acc[4] = {};
#pragma unroll
                    for (int kc = 0; kc < 4; kc++)
#pragma unroll
                        for (int mt = 0; mt < 4; mt++)
                            acc[mt] = __builtin_amdgcn_mfma_f32_16x16x32_f16(afH[mt][kc], bf[kc], acc[mt], 0, 0, 0);

                    float4v t0 = (s & 1) ? acc[1] : acc[0];
                    float4v t1 = (s & 1) ? acc[3] : acc[2];
                    float4v gg = (s & 2) ? t1 : t0;

                    float g0 = gg[0] + bq[0] + (float)xp[0], g1 = gg[1] + bq[1] + (float)xp[1];
                    float g2 = gg[2] + bq[2] + (float)xp[2], g3 = gg[3] + bq[3] + (float)xp[3];
                    float iv = sigf_fast(g0), fv = sigf_fast(g1);
                    float gv = tanhf_fast(g2), ov = sigf_fast(g3);
                    c  = fv * c + iv * gv;
                    hv = ov * tanhf_fast(c);

                    Hl[(cur ^ 1) * (4 * HSTR) + b * HSTR + j] = (_Float16)hv;

                    if (k == 7) {
                        if (tid == 511 && g + 1 < NG2) {
                            unsigned int need = (unsigned int)(8 * (g + 1) + 10);
                            if (need > T2) need = T2;
                            if (ps2 < pf2) ps2 = pf2;
                            while (ps2 < need) { __builtin_amdgcn_s_sleep(2); ps2 = aldu32(pr2); }
                        }
                    }
                    lds_barrier();
                    xp = xp1; xp1 = xpn;
                    cur ^= 1;
                }
            } else {
#pragma unroll
                for (int k = 0; k < 8; k++) {
                    const int t = g * 8 + k;
                    f16x4 xpn = __builtin_bit_cast(f16x4,
                        ald64(x2b + (size_t)((t + 2) & (RING - 1)) * 512));

                    const _Float16* Hc = Hl + cur * (4 * HSTR);
                    f16x8 bf[4];
#pragma unroll
                    for (int kc = 0; kc < 4; kc++)
                        bf[kc] = *(const f16x8*)(Hc + b * HSTR + kc * 32 + quad * 8);

                    float4v acc[4] = {};
#pragma unroll
                    for (int kc = 0; kc < 4; kc++)
#pragma unroll
                        for (int mt = 0; mt < 4; mt++)
                            acc[mt] = __builtin_amdgcn_mfma_f32_16x16x32_f16(afH[mt][kc], bf[kc], acc[mt], 0, 0, 0);

                    float4v t0 = (s & 1) ? acc[1] : acc[0];
                    float4v t1 = (s & 1) ? acc[3] : acc[2];
                    float4v gg = (s & 2) ? t1 : t0;

                    float g0 = gg[0] + bq[0] + (float)xp[0], g1 = gg[1] + bq[1] + (float)xp[1];
                    float g2 = gg[2] + bq[2] + (float)xp[2], g3 = gg[3] + bq[3] + (float)xp[3];
                    float iv = sigf_fast(g0), fv = sigf_fast(g1);
                    float gv = tanhf_fast(g2), ov = sigf_fast(g3);
                    c  = fv * c + iv * gv;
                    hv = ov * tanhf_fast(c);

                    _Float16 hf = (_Float16)hv;
                    ast16(y1p + (size_t)(t & (RING - 1)) * 128,
                          __builtin_bit_cast(unsigned short, hf));
                    Hl[(cur ^ 1) * (4 * HSTR) + b * HSTR + j] = hf;

                    if (k == 7) {
                        // y1(<=8g+6) ACKed (newest {xp2load, y1store} remain)
                        asm volatile("s_waitcnt vmcnt(2)" ::: "memory");
                        if (tid == 0) astu32(pr4, (unsigned int)(g * 8 + 7));
                        if (tid == 511 && g + 1 < NG2) {
                            unsigned int need = (unsigned int)(8 * (g + 1) + 10);
                            if (need > T2) need = T2;
                            if (ps2 < pf2) ps2 = pf2;
                            while (ps2 < need) { __builtin_amdgcn_s_sleep(2); ps2 = aldu32(pr2); }
                            if (g + 1 >= NG + 32) {
                                // y1-ring back-gate: out must have staged g+1-32
                                unsigned int need5 = (unsigned int)(8 * (g + 1 - 32) + 8);
                                if (ps5 < pf5) ps5 = pf5;
                                while (ps5 < need5) { __builtin_amdgcn_s_sleep(2); ps5 = aldu32(pr5); }
                            }
                        }
                    }
                    lds_barrier();
                    xp = xp1; xp1 = xpn;
                    cur ^= 1;
                }
            }
        }
        asm volatile("s_waitcnt vmcnt(0)" ::: "memory");
        __syncthreads();
        if (tid == 0) astu32(pr4, T2);
    } else if (role == 2) {
        // ========== Wih-helper: XP2 = W @ y0 (swapped-operand), 2T ========
        f16x8 bw[4][4];
#pragma unroll
        for (int nt = 0; nt < 4; nt++) {
            int n = (w * 4 + nt) * 16 + col;
            int wrow = (n & 3) * 128 + (n >> 2);
            const float* Wr = eW1 + (size_t)wrow * 128;
#pragma unroll
            for (int kc = 0; kc < 4; kc++) { bw[nt][kc] = cvt8(Wr + kc * 32 + quad * 8); pin(bw[nt][kc]); }
        }

        const int lrow = tid >> 4, lchunk = tid & 15;
        const int lb = lrow & 3, ltr = lrow >> 2;

        for (int g = 0; g < NG2; g++) {
            if (g == NG) {
#pragma unroll
                for (int nt = 0; nt < 4; nt++) {
                    int n = (w * 4 + nt) * 16 + col;
                    int wrow = (n & 3) * 128 + (n >> 2);
                    const float* Wr = dW1 + (size_t)wrow * 128;
#pragma unroll
                    for (int kc = 0; kc < 4; kc++) { bw[nt][kc] = cvt8(Wr + kc * 32 + quad * 8); pin(bw[nt][kc]); }
                }
            }
            if (tid == 0) {
                unsigned int need = (unsigned int)(g * 8 + 8);
                unsigned int psn = aldu32(pr);
                while (psn < need) { __builtin_amdgcn_s_sleep(4); psn = aldu32(pr); }
            }
            __syncthreads();
            {
                int slot = (g * 8 + ltr) & (RING - 1);
                const char* srcp = (const char*)(PB + ((size_t)(p * 4 + lb) * RING + slot) * 128 + lchunk * 8);
                u64 a0 = ald64(srcp);
                u64 a1 = ald64(srcp + 8);
                char* dst = (char*)&Ylh[lrow * YSTR + lchunk * 8];
                *(u64*)dst = a0;
                *(u64*)(dst + 8) = a1;
            }
            lds_barrier();

            float4v acc[2][4] = {};
#pragma unroll
            for (int kc = 0; kc < 4; kc++) {
                f16x8 y0  = *(const f16x8*)&Ylh[col * YSTR + kc * 32 + quad * 8];
                f16x8 y1t = *(const f16x8*)&Ylh[(16 + col) * YSTR + kc * 32 + quad * 8];
#pragma unroll
                for (int nt = 0; nt < 4; nt++) {
                    acc[0][nt] = __builtin_amdgcn_mfma_f32_16x16x32_f16(bw[nt][kc], y0,  acc[0][nt], 0, 0, 0);
                    acc[1][nt] = __builtin_amdgcn_mfma_f32_16x16x32_f16(bw[nt][kc], y1t, acc[1][nt], 0, 0, 0);
                }
            }
            {
                const int bb = col & 3;
#pragma unroll
                for (int mt = 0; mt < 2; mt++) {
                    int trow = mt * 4 + (col >> 2);
                    int slot = (g * 8 + trow) & (RING - 1);
                    _Float16* dst = X2 + ((size_t)(p * 4 + bb) * RING + slot) * 512 + (w * 4) * 16 + quad * 4;
#pragma unroll
                    for (int nt = 0; nt < 4; nt++)
                        ast64(dst + nt * 16, pack4(acc[mt][nt]));
                }
            }
            asm volatile("s_waitcnt vmcnt(0)" ::: "memory");
            __syncthreads();
            if (tid == 0) astu32(pr2, (unsigned int)(g * 8 + 8));
        }
    } else if (role == 3) {
        // ========== xph: XP = x @ eW0^T (PERM, swapped) -> X1, exits at NG =
        f16x8 bw[4][4];
#pragma unroll
        for (int nt = 0; nt < 4; nt++) {
            int n = (w * 4 + nt) * 16 + col;
            int wrow = (n & 3) * 128 + (n >> 2);
            const float* Wr = eW0 + (size_t)wrow * 128;
#pragma unroll
            for (int kc = 0; kc < 4; kc++) { bw[nt][kc] = cvt8(Wr + kc * 32 + quad * 8); pin(bw[nt][kc]); }
        }

        const int lrow = tid >> 4, lchunk = tid & 15;
        const int lb = lrow & 3, ltr = lrow >> 2;
        const float* xsrc = xin + (size_t)(p * 4 + lb) * T * 128 + lchunk * 8;

        for (int g = 0; g < NG; g++) {
            // lap-gate: don't overwrite xp slots the producer hasn't read.
            if (g >= 32 && tid == 0) {
                unsigned int need = (unsigned int)(8 * (g - 32));
                unsigned int psn = aldu32(pr);
                while (psn < need) { __builtin_amdgcn_s_sleep(4); psn = aldu32(pr); }
            }
            __syncthreads();
            {   // stage x granule, f32 -> f16
                f16x8 xv = cvt8(xsrc + (size_t)(g * 8 + ltr) * 128);
                u64p w2 = __builtin_bit_cast(u64p, xv);
                char* dst = (char*)&Ylh[lrow * YSTR + lchunk * 8];
                *(u64*)dst = w2.a;
                *(u64*)(dst + 8) = w2.b;
            }
            lds_barrier();

            float4v acc[2][4] = {};
#pragma unroll
            for (int kc = 0; kc < 4; kc++) {
                f16x8 y0  = *(const f16x8*)&Ylh[col * YSTR + kc * 32 + quad * 8];
                f16x8 y1t = *(const f16x8*)&Ylh[(16 + col) * YSTR + kc * 32 + quad * 8];
#pragma unroll
                for (int nt = 0; nt < 4; nt++) {
                    acc[0][nt] = __builtin_amdgcn_mfma_f32_16x16x32_f16(bw[nt][kc], y0,  acc[0][nt], 0, 0, 0);
                    acc[1][nt] = __builtin_amdgcn_mfma_f32_16x16x32_f16(bw[nt][kc], y1t, acc[1][nt], 0, 0, 0);
                }
            }
            {
                const int bb = col & 3;
#pragma unroll
                for (int mt = 0; mt < 2; mt++) {
                    int trow = mt * 4 + (col >> 2);
                    int slot = (g * 8 + trow) & (RING - 1);
                    _Float16* dst = X1 + ((size_t)(p * 4 + bb) * RING + slot) * 512 + (w * 4) * 16 + quad * 4;
#pragma unroll
                    for (int nt = 0; nt < 4; nt++)
                        ast64(dst + nt * 16, pack4(acc[mt][nt]));
                }
            }
            asm volatile("s_waitcnt vmcnt(0)" ::: "memory");
            __syncthreads();
            if (tid == 0) astu32(pr3, (unsigned int)(g * 8 + 8));
        }
    } else {
        // ========== out: d_out = y1 @ oW^T + ob; runs g = NG..2NG-1 =======
        f16x8 bo[4];
#pragma unroll
        for (int kc = 0; kc < 4; kc++) { bo[kc] = cvt8(oW + (size_t)(w * 16 + col) * 128 + kc * 32 + quad * 8); pin(bo[kc]); }
        float4v bv4 = *(const float4v*)(ob + w * 16 + quad * 4);

        const int lrow = tid >> 4, lchunk = tid & 15;
        const int lb = lrow & 3, ltr = lrow >> 2;

        for (int gg = 0; gg < NG; gg++) {
            const int g = NG + gg;
            if (tid == 0) {
                unsigned int need = (unsigned int)(g * 8 + 8);
                unsigned int psn = aldu32(pr4);
                while (psn < need) { __builtin_amdgcn_s_sleep(4); psn = aldu32(pr4); }
            }
            __syncthreads();   // also fences prior granule's Ylh reads
            {
                int slot = (g * 8 + ltr) & (RING - 1);
                const char* srcp = (const char*)(Y1 + ((size_t)(p * 4 + lb) * RING + slot) * 128 + lchunk * 8);
                u64 a0 = ald64(srcp);
                u64 a1 = ald64(srcp + 8);
                char* dst = (char*)&Ylh[lrow * YSTR + lchunk * 8];
                *(u64*)dst = a0;
                *(u64*)(dst + 8) = a1;
            }
            lds_barrier();
            // release consumed-progress: granule g's ring slots fully staged.
            if (tid == 0) astu32(pr5, (unsigned int)(g * 8 + 8));

            float4v acc[2] = {};
#pragma unroll
            for (int kc = 0; kc < 4; kc++) {
                f16x8 y0  = *(const f16x8*)&Ylh[col * YSTR + kc * 32 + quad * 8];
                f16x8 y1t = *(const f16x8*)&Ylh[(16 + col) * YSTR + kc * 32 + quad * 8];
                acc[0] = __builtin_amdgcn_mfma_f32_16x16x32_f16(bo[kc], y0,  acc[0], 0, 0, 0);
                acc[1] = __builtin_amdgcn_mfma_f32_16x16x32_f16(bo[kc], y1t, acc[1], 0, 0, 0);
            }
            {
                const int bb = col & 3;
#pragma unroll
                for (int mt = 0; mt < 2; mt++) {
                    int trow = mt * 4 + (col >> 2);
                    float4v v = acc[mt];
                    v[0] += bv4[0]; v[1] += bv4[1]; v[2] += bv4[2]; v[3] += bv4[3];
                    *(float4v*)(outp + ((size_t)(p * 4 + bb) * T + gg * 8 + trow) * 128 + w * 16 + quad * 4) = v;
                }
            }
        }
    }
}

// ---------------------------------------------------------------------------
// Host: memset + ONE launch (80 WGs x 512 threads).
//   ws map: X1 [0,16M) | X2 [16,32M) | PB [32,36M) | Y1 [36,40M) | prog @40M
// ---------------------------------------------------------------------------
extern "C" void kernel_launch(void* const* d_in, const int* in_sizes, int n_in,
                              void* d_out, int out_size, void* d_ws, size_t ws_size,
                              hipStream_t stream)
{
    const float* x    = (const float*)d_in[0];
    const float* eW0  = (const float*)d_in[1];
    const float* eU0  = (const float*)d_in[2];
    const float* eb0i = (const float*)d_in[3];
    const float* eb0h = (const float*)d_in[4];
    const float* eW1  = (const float*)d_in[5];
    const float* eU1  = (const float*)d_in[6];
    const float* eb1i = (const float*)d_in[7];
    const float* eb1h = (const float*)d_in[8];
    const float* dU0  = (const float*)d_in[10];
    const float* db0i = (const float*)d_in[11];
    const float* db0h = (const float*)d_in[12];
    const float* dW1  = (const float*)d_in[13];
    const float* dU1  = (const float*)d_in[14];
    const float* db1i = (const float*)d_in[15];
    const float* db1h = (const float*)d_in[16];
    const float* oW   = (const float*)d_in[17];
    const float* ob   = (const float*)d_in[18];

    char* ws = (char*)d_ws;
    _Float16* X1 = (_Float16*)(ws);                  // 16MB
    _Float16* X2 = (_Float16*)(ws + (16u << 20));    // 16MB
    _Float16* PB = (_Float16*)(ws + (32u << 20));    //  4MB
    _Float16* Y1 = (_Float16*)(ws + (36u << 20));    //  4MB
    unsigned int* pg = (unsigned int*)(ws + (40u << 20));

    hipMemsetAsync((void*)pg, 0, 8192, stream);

    lstm_mega<<<dim3(80), dim3(512), 0, stream>>>(
        eU0, eb0i, eb0h, dU0, db0i, db0h,
        eU1, eb1i, eb1h, dU1, db1i, db1h,
        eW1, dW1, eW0, x, oW, ob, (float*)d_out,
        PB, X2, X1, Y1,
        pg, pg + 256, pg + 512, pg + 768, pg + 1024, Tlen);
}